// Round 2
// baseline (357.355 us; speedup 1.0000x reference)
//
#include <hip/hip_runtime.h>

#define SEQ 550
#define MID 100
#define TPB 448

typedef _Float16 half2_t __attribute__((ext_vector_type(2)));

union H2I { int i; half2_t h; ushort2 u2; };

__device__ __forceinline__ float fdot2(half2_t a, half2_t b, float c) {
    return __builtin_amdgcn_fdot2(a, b, c, false);
}
__device__ __forceinline__ float sigm(float x) { return 1.0f / (1.0f + __expf(-x)); }
__device__ __forceinline__ float tanh_f(float x) { return 1.0f - 2.0f / (__expf(2.0f * x) + 1.0f); }
__device__ __forceinline__ half2_t i2h(int v) { H2I u; u.i = v; return u.h; }

// sum across the 4 lanes of a quad: xor1 then xor2 via DPP quad_perm (VALU only)
__device__ __forceinline__ float qsum(float x) {
    int a = __builtin_amdgcn_update_dpp(0, __float_as_int(x), 0xB1, 0xF, 0xF, true); // [1,0,3,2]
    float y = x + __int_as_float(a);
    int b = __builtin_amdgcn_update_dpp(0, __float_as_int(y), 0x4E, 0xF, 0xF, true); // [2,3,0,1]
    return y + __int_as_float(b);
}

// Unified per-step vector (2 buffers x 256B). Four 64B segments, one per p.
// Segment p: positions 0..12 = h-half2 (h2 indices segbase[p]..), pos 13..14 = e-half2, pos 15 unused.
// p0: h2 0..12,  e0,e1 | p1: h2 13..25, e2,pad | p2: h2 26..37,pad, e3,pad | p3: h2 38..49,pad, e4,pad
// Pads are zeroed once and never written; matching weights are zero.

__global__ __launch_bounds__(TPB, 1) void gru_fused(
    const int*   __restrict__ x,
    const float* __restrict__ hidden,
    const float* __restrict__ embed,
    const float* __restrict__ w_ih,
    const float* __restrict__ w_hh,
    const float* __restrict__ b_ih,
    const float* __restrict__ b_hh,
    const float* __restrict__ fc_w,
    const float* __restrict__ fc_b,
    float*       __restrict__ out)
{
    __shared__ __align__(16) int   seqbuf[SEQ * 5];   // e_t as 5 packed half2 ints: 11 KB
    __shared__ __align__(16) int   hbuf[128];         // 2 x 256B unified [h|e] vectors
    __shared__ float partial[MID];

    const int  tid = threadIdx.x;
    const bool act = tid < 4 * MID;          // 400 workers: quad (4u..4u+3) owns unit u
    const int  u   = tid >> 2;
    const int  p   = tid & 3;

    // ---- zero h buffers (incl. permanent pads) + stage embedded sequence as fp16 ----
    if (tid < 128) hbuf[tid] = 0;
    for (int i = tid; i < SEQ * 5; i += TPB) {
        int t = i / 5, j = i - 5 * t;
        const float* ep = embed + x[t] * 10 + 2 * j;
        H2I c; c.h = half2_t{(_Float16)ep[0], (_Float16)ep[1]};
        seqbuf[i] = c.i;
    }

    // ---- per-thread weights: 3 gate rows of unit u, 15 half2 positions each ----
    half2_t w0[15], w1[15], wn[15];
    float b0 = 0.f, b1 = 0.f, b2 = 0.f, b3 = 0.f, hreg = 0.f, fcw = 0.f;
    int hw_off = 0;

    if (act) {
        const int segbase[4] = {0, 13, 26, 38};
        const int segcnt[4]  = {13, 13, 12, 12};
        const int ebase[4]   = {0, 2, 3, 4};
        const int ecnt[4]    = {2, 1, 1, 1};

        #pragma unroll
        for (int r = 0; r < 3; r++) {
            const float* WH = w_hh + (r * MID + u) * MID;
            const float* WI = w_ih + (r * MID + u) * 10;
            half2_t* W = (r == 0) ? w0 : (r == 1) ? w1 : wn;
            #pragma unroll
            for (int pos = 0; pos < 13; pos++) {
                int m  = segbase[p] + pos;
                int mc = m < 49 ? m : 49;                 // clamp to stay in-bounds
                half2_t wv = half2_t{(_Float16)WH[2 * mc], (_Float16)WH[2 * mc + 1]};
                W[pos] = (pos < segcnt[p]) ? wv : half2_t{(_Float16)0.f, (_Float16)0.f};
            }
            #pragma unroll
            for (int j = 0; j < 2; j++) {
                int m  = ebase[p] + j;
                int mc = m < 4 ? m : 4;
                half2_t wv = half2_t{(_Float16)WI[2 * mc], (_Float16)WI[2 * mc + 1]};
                W[13 + j] = (j < ecnt[p]) ? wv : half2_t{(_Float16)0.f, (_Float16)0.f};
            }
        }
        if (p == 0) {                         // biases once per quad (qsum would 4x them)
            b0 = b_ih[u]           + b_hh[u];
            b1 = b_ih[MID + u]     + b_hh[MID + u];
            b2 = b_ih[2 * MID + u];           // input side of n-gate
            b3 = b_hh[2 * MID + u];           // hidden side of n-gate (r-scaled)
        }
        hreg = hidden[u];
        fcw  = fc_w[u];
        // h-write slot for unit u
        int m   = u >> 1;
        int seg = (m < 13) ? 0 : (m < 26) ? 1 : (m < 38) ? 2 : 3;
        hw_off  = seg * 64 + (m - segbase[seg]) * 4 + (u & 1) * 2;
    }
    float fcb = (tid == 0) ? fc_b[0] : 0.0f;

    // helper lanes: tids 400..404 copy e_{t+1} into the next buffer each step
    const int he = tid - 400;                                   // 0..4 for helpers
    const int my_eslot = (he == 0) ? 52 : (he == 1) ? 56 :
                         (he == 2) ? 116 : (he == 3) ? 180 : 244;

    __syncthreads();

    // ---- init buffer 0: h0 + e_0 ----
    if (act && p == 0)
        *(_Float16*)((char*)hbuf + hw_off) = (_Float16)hreg;
    if (tid >= 400 && tid < 405)
        *(int*)((char*)hbuf + my_eslot) = seqbuf[he];
    __syncthreads();

    const char* rdbase = (const char*)hbuf + p * 64;

    #pragma unroll 1
    for (int t = 0; t < SEQ; t++) {
        const int rpar = (t & 1) << 8;
        const int wpar = rpar ^ 256;
        if (act) {
            const int4* qp = (const int4*)(rdbase + rpar);
            int4 q0 = qp[0], q1 = qp[1], q2 = qp[2], q3 = qp[3];
            float s0 = b0, s1 = b1, s2 = b2, s3 = b3;
            half2_t v;
            v = i2h(q0.x); s0 = fdot2(w0[0],  v, s0); s1 = fdot2(w1[0],  v, s1); s3 = fdot2(wn[0],  v, s3);
            v = i2h(q0.y); s0 = fdot2(w0[1],  v, s0); s1 = fdot2(w1[1],  v, s1); s3 = fdot2(wn[1],  v, s3);
            v = i2h(q0.z); s0 = fdot2(w0[2],  v, s0); s1 = fdot2(w1[2],  v, s1); s3 = fdot2(wn[2],  v, s3);
            v = i2h(q0.w); s0 = fdot2(w0[3],  v, s0); s1 = fdot2(w1[3],  v, s1); s3 = fdot2(wn[3],  v, s3);
            v = i2h(q1.x); s0 = fdot2(w0[4],  v, s0); s1 = fdot2(w1[4],  v, s1); s3 = fdot2(wn[4],  v, s3);
            v = i2h(q1.y); s0 = fdot2(w0[5],  v, s0); s1 = fdot2(w1[5],  v, s1); s3 = fdot2(wn[5],  v, s3);
            v = i2h(q1.z); s0 = fdot2(w0[6],  v, s0); s1 = fdot2(w1[6],  v, s1); s3 = fdot2(wn[6],  v, s3);
            v = i2h(q1.w); s0 = fdot2(w0[7],  v, s0); s1 = fdot2(w1[7],  v, s1); s3 = fdot2(wn[7],  v, s3);
            v = i2h(q2.x); s0 = fdot2(w0[8],  v, s0); s1 = fdot2(w1[8],  v, s1); s3 = fdot2(wn[8],  v, s3);
            v = i2h(q2.y); s0 = fdot2(w0[9],  v, s0); s1 = fdot2(w1[9],  v, s1); s3 = fdot2(wn[9],  v, s3);
            v = i2h(q2.z); s0 = fdot2(w0[10], v, s0); s1 = fdot2(w1[10], v, s1); s3 = fdot2(wn[10], v, s3);
            v = i2h(q2.w); s0 = fdot2(w0[11], v, s0); s1 = fdot2(w1[11], v, s1); s3 = fdot2(wn[11], v, s3);
            v = i2h(q3.x); s0 = fdot2(w0[12], v, s0); s1 = fdot2(w1[12], v, s1); s3 = fdot2(wn[12], v, s3);
            v = i2h(q3.y); s0 = fdot2(w0[13], v, s0); s1 = fdot2(w1[13], v, s1); s2 = fdot2(wn[13], v, s2);
            v = i2h(q3.z); s0 = fdot2(w0[14], v, s0); s1 = fdot2(w1[14], v, s1); s2 = fdot2(wn[14], v, s2);

            float ar  = qsum(s0);
            float az  = qsum(s1);
            float gin = qsum(s2);
            float ghn = qsum(s3);

            float r = sigm(ar);
            float z = sigm(az);
            float n = tanh_f(gin + r * ghn);
            hreg = n + z * (hreg - n);                    // exact fp32 state
            if (p == 0)
                *(_Float16*)((char*)hbuf + wpar + hw_off) = (_Float16)hreg;
        } else if (tid >= 400 && tid < 405 && t + 1 < SEQ) {
            *(int*)((char*)hbuf + wpar + my_eslot) = seqbuf[(t + 1) * 5 + he];
        }
        __syncthreads();   // single barrier per step; ping-pong buffers
    }

    // ---- epilogue: sigmoid(relu(h) . fc_w + fc_b) ----
    if (act && p == 0) partial[u] = fmaxf(hreg, 0.0f) * fcw;
    __syncthreads();
    if (tid == 0) {
        float s = fcb;
        const float4* pp = (const float4*)partial;
        #pragma unroll
        for (int k = 0; k < 25; k++) {
            float4 f = pp[k];
            s += (f.x + f.y) + (f.z + f.w);
        }
        out[0] = sigm(s);
    }
}

extern "C" void kernel_launch(void* const* d_in, const int* in_sizes, int n_in,
                              void* d_out, int out_size, void* d_ws, size_t ws_size,
                              hipStream_t stream) {
    const int*   x      = (const int*)  d_in[0];
    const float* hidden = (const float*)d_in[1];
    const float* embed  = (const float*)d_in[2];
    const float* w_ih   = (const float*)d_in[3];
    const float* w_hh   = (const float*)d_in[4];
    const float* b_ih   = (const float*)d_in[5];
    const float* b_hh   = (const float*)d_in[6];
    const float* fc_w   = (const float*)d_in[7];
    const float* fc_b   = (const float*)d_in[8];
    float*       out    = (float*)d_out;

    gru_fused<<<1, TPB, 0, stream>>>(x, hidden, embed, w_ih, w_hh,
                                     b_ih, b_hh, fc_w, fc_b, out);
}